// Round 11
// baseline (771.066 us; speedup 1.0000x reference)
//
#include <hip/hip_runtime.h>
#include <cstdint>

// ---------------------------------------------------------------------------
// Block_7584912244953 on MI355X (gfx950).
//   P_xx = Wp1_xx @ e (3 big GEMMs, fp32 A DIRECT-TO-REGISTER: no LDS for A;
//                      B via gload_lds + counted vmcnt; splitK=4 atomics)
//   Ah   = adj @ h    (sparse ballot-scan gather, deg~8)
//   12 batched projections -> per-node 8x8 SDPA -> FFN
// gemm_f32a v4 ("areg"): 4 waves, wave = 32 rows x 128 cols (acc 2x8).
// Each A element is consumed by exactly one lane -> A loads go straight into
// MFMA operand registers (4x global_load_dwordx4/thread/iter, 16 rows x 128B
// fully-used lines per wave-load). A-stream is sync-free (compiler-tracked
// register deps), decoupled from barriers; LDS = 16KB (B dbuf only) -> 3-4
// blocks/CU -> ~4x the in-flight bytes of the LDS-staged designs (R7-R10's
// concurrency ceiling).
// bf16 "swz" layout: 16B-chunk c of row r stored at c ^ ((r>>1)&3) within each
// 64B window -> MFMA fragment ds_read_b128 is 2-way (free).
// ---------------------------------------------------------------------------

typedef unsigned short u16;
typedef __bf16 bf16x8 __attribute__((ext_vector_type(8)));
typedef float f32x4 __attribute__((ext_vector_type(4)));

__device__ __forceinline__ u16 f2bf(float f) {
    unsigned u = __float_as_uint(f);
    return (u16)((u + 0x7fffu + ((u >> 16) & 1u)) >> 16);  // RNE
}
__device__ __forceinline__ float bf2f(u16 u) { return __uint_as_float(((unsigned)u) << 16); }
__device__ __forceinline__ float gelu_exact(float x) {
    return 0.5f * x * (1.0f + erff(x * 0.70710678118654752f));
}

__device__ __forceinline__ void gload_lds16(const void* g, void* l) {
    __builtin_amdgcn_global_load_lds(
        (const __attribute__((address_space(1))) unsigned int*)(uintptr_t)g,
        (__attribute__((address_space(3))) unsigned int*)(unsigned int)(uintptr_t)l,
        16, 0, 0);
}

#define SCHED0 __builtin_amdgcn_sched_barrier(0)

// bijective XCD-aware block swizzle (gridDim product % 8 == 0)
__device__ __forceinline__ void swz_block(int& bx, int& by, int& bz) {
    const int nx = gridDim.x, ny = gridDim.y;
    const int nwg = nx * ny * gridDim.z;
    int lin = blockIdx.x + nx * (blockIdx.y + ny * blockIdx.z);
    const int chunk = nwg >> 3;
    lin = (lin & 7) * chunk + (lin >> 3);
    bx = lin % nx;
    lin /= nx;
    by = lin % ny;
    bz = lin / ny;
}

// ---------------------------------------------------------------------------
// fp32 -> bf16 convert; SWZ=true emits swz layout (assumes 512-elem rows)
// ---------------------------------------------------------------------------
template <bool SWZ>
__global__ __launch_bounds__(256) void cvt_f32_bf16(const float* __restrict__ in,
                                                    u16* __restrict__ out, size_t n8) {
    size_t i = (size_t)blockIdx.x * 256 + threadIdx.x;
    size_t stride = (size_t)gridDim.x * 256;
    for (; i < n8; i += stride) {
        float4 a = ((const float4*)in)[i * 2];
        float4 b = ((const float4*)in)[i * 2 + 1];
        u16 r[8] = {f2bf(a.x), f2bf(a.y), f2bf(a.z), f2bf(a.w),
                    f2bf(b.x), f2bf(b.y), f2bf(b.z), f2bf(b.w)};
        size_t o = i;
        if constexpr (SWZ) o = (i & ~(size_t)63) | ((i & 63) ^ ((i >> 7) & 3));
        ((uint4*)out)[o] = *(const uint4*)r;
    }
}

// ---------------------------------------------------------------------------
// fp32 (RxC) -> bf16 transposed (CxR), swz output layout
// ---------------------------------------------------------------------------
__global__ __launch_bounds__(256) void transpose_cvt(const float* __restrict__ in,
                                                     u16* __restrict__ out, int R, int C) {
    __shared__ float tile[32][33];
    int c0 = blockIdx.x * 32, r0 = blockIdx.y * 32;
    int tx = threadIdx.x & 31, ty = threadIdx.x >> 5;
#pragma unroll
    for (int i = 0; i < 4; ++i)
        tile[ty + i * 8][tx] = in[(size_t)(r0 + ty + i * 8) * C + c0 + tx];
    __syncthreads();
#pragma unroll
    for (int i = 0; i < 4; ++i) {
        int orow = c0 + ty + i * 8;
        out[(size_t)orow * R + ((r0 + tx) ^ (((orow >> 1) & 3) << 3))] = f2bf(tile[tx][ty + i * 8]);
    }
}

struct W12 { const float* in[12]; u16* out[12]; };
__global__ __launch_bounds__(256) void transpose_cvt12(W12 w) {
    __shared__ float tile[32][33];
    const float* in = w.in[blockIdx.z];
    u16* out = w.out[blockIdx.z];
    int c0 = blockIdx.x * 32, r0 = blockIdx.y * 32;
    int tx = threadIdx.x & 31, ty = threadIdx.x >> 5;
#pragma unroll
    for (int i = 0; i < 4; ++i)
        tile[ty + i * 8][tx] = in[(size_t)(r0 + ty + i * 8) * 512 + c0 + tx];
    __syncthreads();
#pragma unroll
    for (int i = 0; i < 4; ++i) {
        int orow = c0 + ty + i * 8;
        out[(size_t)orow * 512 + ((r0 + tx) ^ (((orow >> 1) & 3) << 3))] = f2bf(tile[tx][ty + i * 8]);
    }
}

// bf16 (RxC, plain) -> bf16 transposed (CxR, swz)
__global__ __launch_bounds__(256) void transpose_u16(const u16* __restrict__ in,
                                                     u16* __restrict__ out, int R, int C) {
    __shared__ u16 tile[32][34];
    int c0 = blockIdx.x * 32, r0 = blockIdx.y * 32;
    int tx = threadIdx.x & 31, ty = threadIdx.x >> 5;
#pragma unroll
    for (int i = 0; i < 4; ++i)
        tile[ty + i * 8][tx] = in[(size_t)(r0 + ty + i * 8) * C + c0 + tx];
    __syncthreads();
#pragma unroll
    for (int i = 0; i < 4; ++i) {
        int orow = c0 + ty + i * 8;
        out[(size_t)orow * R + ((r0 + tx) ^ (((orow >> 1) & 3) << 3))] = tile[tx][ty + i * 8];
    }
}

// ---------------------------------------------------------------------------
// RMSNorm (rows x 512) fp32 -> bf16; SWZ selects output layout
// ---------------------------------------------------------------------------
template <bool SWZ>
__global__ __launch_bounds__(256) void rmsnorm_bf16(const float* __restrict__ x,
                                                    const float* __restrict__ g,
                                                    u16* __restrict__ out) {
    int row = blockIdx.x, tid = threadIdx.x;
    const float* xr = x + (size_t)row * 512;
    float2 v = *(const float2*)(xr + tid * 2);
    float ss = v.x * v.x + v.y * v.y;
#pragma unroll
    for (int o = 32; o; o >>= 1) ss += __shfl_down(ss, o);
    __shared__ float red[4];
    if ((tid & 63) == 0) red[tid >> 6] = ss;
    __syncthreads();
    float tot = red[0] + red[1] + red[2] + red[3];
    float rs = rsqrtf(tot * (1.0f / 512.0f) + 1e-6f);
    unsigned pack = (unsigned)f2bf(v.x * rs * g[tid * 2]) |
                    ((unsigned)f2bf(v.y * rs * g[tid * 2 + 1]) << 16);
    int o32 = SWZ ? (tid ^ (((row >> 1) & 3) << 2)) : tid;
    ((unsigned*)out)[(size_t)row * 256 + o32] = pack;
}

// ---------------------------------------------------------------------------
// Sparse Ah = adj @ h (adj ~0.2% dense binary). One wave per node. swz h/out.
// ---------------------------------------------------------------------------
__global__ __launch_bounds__(256) void adj_spmm(const float* __restrict__ adj,
                                                const u16* __restrict__ h,
                                                u16* __restrict__ out) {
    const int wave = threadIdx.x >> 6, lane = threadIdx.x & 63;
    const int n = blockIdx.x * 4 + wave;
    const float* arow = adj + (size_t)n * 4096;
    float acc[8] = {0.f, 0.f, 0.f, 0.f, 0.f, 0.f, 0.f, 0.f};
    for (int j = 0; j < 64; ++j) {
        float v = arow[j * 64 + lane];
        unsigned long long mask = __ballot(v != 0.0f);
        while (mask) {
            int bit = __ffsll((long long)mask) - 1;
            mask &= mask - 1;
            int m = j * 64 + bit;
            float w = __shfl(v, bit);
            int cs = (lane & ~3) | ((lane & 3) ^ ((m >> 1) & 3));
            uint4 q = *(const uint4*)(h + (size_t)m * 512 + cs * 8);
            const u16* qu = (const u16*)&q;
#pragma unroll
            for (int t = 0; t < 8; ++t) acc[t] += w * bf2f(qu[t]);
        }
    }
    int co = (lane & ~3) | ((lane & 3) ^ ((n >> 1) & 3));
    u16 r[8];
#pragma unroll
    for (int t = 0; t < 8; ++t) r[t] = f2bf(acc[t]);
    *(uint4*)(out + (size_t)n * 512 + co * 8) = *(const uint4*)r;
}

// ---------------------------------------------------------------------------
// bf16 GEMM tile body (m97 structure): 128x128 tile, BK=32, single LDS buf,
// 4 waves (2x2), 4x4 frags of v_mfma_f32_16x16x32_bf16. A, Bt swz bf16.
// MODE: 0 bf16 plain store, 1 bf16 bias+gelu swz store, 3 f32 atomicAdd(+bias)
// ---------------------------------------------------------------------------
template <int MODE>
__device__ __forceinline__ void gemm_tile_body(const u16* __restrict__ A,
                                               const u16* __restrict__ Bt,
                                               int N, int K, int k_begin, int k_end,
                                               int rowStart, int colStart,
                                               void* __restrict__ C,
                                               const float* __restrict__ bias) {
    __shared__ u16 Asm[128 * 32];
    __shared__ u16 Bsm[128 * 32];
    const int tid = threadIdx.x;
    const int wave = tid >> 6, lane = tid & 63;
    const int wr = wave >> 1, wc = wave & 1;

    f32x4 acc[4][4];
#pragma unroll
    for (int m = 0; m < 4; ++m)
#pragma unroll
        for (int n = 0; n < 4; ++n) acc[m][n] = f32x4{0.f, 0.f, 0.f, 0.f};

    const int off0 = (wave * 2 + 0) * 1024 + lane * 16;  // byte in 8KB tile
    const int off1 = (wave * 2 + 1) * 1024 + lane * 16;
    const int r0 = off0 >> 6, k0e = (off0 & 63) >> 1;
    const int r1 = off1 >> 6, k1e = (off1 & 63) >> 1;
    const size_t Arow0 = (size_t)(rowStart + r0) * K + k0e;
    const size_t Arow1 = (size_t)(rowStart + r1) * K + k1e;
    const size_t Brow0 = (size_t)(colStart + r0) * K + k0e;
    const size_t Brow1 = (size_t)(colStart + r1) * K + k1e;
    u16* As0 = &Asm[(wave * 2 + 0) * 512];
    u16* As1 = &Asm[(wave * 2 + 1) * 512];
    u16* Bs0 = &Bsm[(wave * 2 + 0) * 512];
    u16* Bs1 = &Bsm[(wave * 2 + 1) * 512];

    const int rsel = lane & 15, ksel = lane >> 4;
    const int fsw = (ksel ^ ((rsel >> 1) & 3)) << 3;  // swz fragment chunk

    for (int kk = k_begin; kk < k_end; kk += 32) {
        gload_lds16(A + Arow0 + kk, As0);
        gload_lds16(A + Arow1 + kk, As1);
        gload_lds16(Bt + Brow0 + kk, Bs0);
        gload_lds16(Bt + Brow1 + kk, Bs1);
        __syncthreads();
        bf16x8 aF[4], bF[4];
#pragma unroll
        for (int m = 0; m < 4; ++m)
            aF[m] = *(const bf16x8*)&Asm[(wr * 64 + m * 16 + rsel) * 32 + fsw];
#pragma unroll
        for (int n = 0; n < 4; ++n)
            bF[n] = *(const bf16x8*)&Bsm[(wc * 64 + n * 16 + rsel) * 32 + fsw];
#pragma unroll
        for (int m = 0; m < 4; ++m)
#pragma unroll
            for (int n = 0; n < 4; ++n)
                acc[m][n] = __builtin_amdgcn_mfma_f32_16x16x32_bf16(aF[m], bF[n], acc[m][n], 0, 0, 0);
        __syncthreads();
    }

    const int cq = (lane >> 4) * 4, cr = lane & 15;
#pragma unroll
    for (int m = 0; m < 4; ++m) {
#pragma unroll
        for (int n = 0; n < 4; ++n) {
            int col = colStart + wc * 64 + n * 16 + cr;
#pragma unroll
            for (int j = 0; j < 4; ++j) {
                int row = rowStart + wr * 64 + m * 16 + cq + j;
                float v = acc[m][n][j];
                if constexpr (MODE == 0) {
                    ((u16*)C)[(size_t)row * N + col] = f2bf(v);
                } else if constexpr (MODE == 1) {
                    v = gelu_exact(v + bias[col]);
                    ((u16*)C)[(size_t)row * N + (col ^ (((row >> 1) & 3) << 3))] = f2bf(v);
                } else {
                    if (bias) v += bias[col];
                    atomicAdd(&((float*)C)[(size_t)row * N + col], v);
                }
            }
        }
    }
}

template <int MODE>
__global__ __launch_bounds__(256) void gemm_bt(const u16* __restrict__ A,
                                               const u16* __restrict__ Bt,
                                               void* __restrict__ C,
                                               const float* __restrict__ bias,
                                               int N, int K, int kLen) {
    int bx, by, bz;
    swz_block(bx, by, bz);
    const float* bb = (MODE == 3) ? ((bz == 0) ? bias : nullptr) : bias;
    int kb = bz * kLen;
    gemm_tile_body<MODE>(A, Bt, N, K, kb, kb + kLen, by * 128, bx * 128, C, bb);
}

// 12 batched projections: C[z](4096x512) = A[z] @ W[z]^T (plain bf16 out)
struct Small12 { const u16* A[12]; const u16* W[12]; u16* C[12]; };
__global__ __launch_bounds__(256) void gemm_small12(Small12 s) {
    int bx, by, bz;
    swz_block(bx, by, bz);
    gemm_tile_body<0>(s.A[bz], s.W[bz], 512, 512, 0, 512, by * 128, bx * 128, s.C[bz], nullptr);
}

// ---------------------------------------------------------------------------
// Big GEMM v4 "areg", fp32 A: C(4096x512) += A(4096xK fp32) @ Bt(512xK swz).
// 256 threads, 4 waves; wave w owns rows [w*32, w*32+32) x all 128 cols of
// the block's column strip (acc 2x8). A loads go DIRECTLY to registers:
// thread (wave,lane) needs rows wave*32 + m*16 + (lane&15), k-chunk
// (lane>>4)*8 — exactly 4 float4 loads/iter, no LDS, no cross-lane sharing.
// B staged via gload_lds (dbuf 16KB) with counted vmcnt + raw barriers.
// Per iter: LOADA(t+1)+STAGEB(t+1) [4+2 vmem] -> vmcnt(6) -> barrier ->
//           COMPUTE(t) -> barrier.
// grid (4,32,12) swizzled; splitK=4 (kLen=4096, nt=128).
// ---------------------------------------------------------------------------
struct Big3 { const float* A[3]; };
__global__ __launch_bounds__(256, 3) void gemm_f32a(Big3 ba, const u16* __restrict__ Bt,
                                                    float* __restrict__ C0, int K,
                                                    int zPerMat, int kLen) {
    __shared__ u16 Bsm[2][4096];   // bf16 B tiles (128 rows x 64B), swz layout
    int bx, by, bz;
    swz_block(bx, by, bz);
    const int mat = bz / zPerMat, ks = bz - mat * zPerMat;
    const float* __restrict__ A = ba.A[mat];
    float* __restrict__ C = C0 + (size_t)mat * (4096 * 512);
    const int rowStart = by * 128, colStart = bx * 128;
    const int k0 = ks * kLen;

    const int tid = threadIdx.x;
    const int wave = tid >> 6, lane = tid & 63;
    const int rsel = lane & 15, ksel = lane >> 4;

    f32x4 acc[2][8];
#pragma unroll
    for (int mm = 0; mm < 2; ++mm)
#pragma unroll
        for (int n = 0; n < 8; ++n) acc[mm][n] = f32x4{0.f, 0.f, 0.f, 0.f};

    // A register-load addresses (element offsets; add kk at use)
    const float* Ap0 = A + (size_t)(rowStart + wave * 32 + 0 * 16 + rsel) * K + ksel * 8;
    const float* Ap1 = A + (size_t)(rowStart + wave * 32 + 1 * 16 + rsel) * K + ksel * 8;

    // B staging (swz bf16, gload_lds): 8 slices of 1KB; wave w owns 2w, 2w+1
    const int off0 = (wave * 2 + 0) * 1024 + lane * 16;
    const int off1 = (wave * 2 + 1) * 1024 + lane * 16;
    const int br0 = off0 >> 6, bk0 = (off0 & 63) >> 1;
    const int br1 = off1 >> 6, bk1 = (off1 & 63) >> 1;
    const u16* Bp0 = Bt + (size_t)(colStart + br0) * K + bk0;
    const u16* Bp1 = Bt + (size_t)(colStart + br1) * K + bk1;
    const int ws0 = (wave * 2 + 0) * 512, ws1 = (wave * 2 + 1) * 512;

    const int fsw = (ksel ^ ((rsel >> 1) & 3)) << 3;

    auto STAGEB = [&](int buf, int kk) {
        gload_lds16(Bp0 + kk, &Bsm[buf][ws0]);
        gload_lds16(Bp1 + kk, &Bsm[buf][ws1]);
    };
    auto COMPUTE = [&](int buf, float4 a0, float4 a1, float4 a2, float4 a3) {
        bf16x8 aF[2];
        aF[0][0] = (__bf16)a0.x; aF[0][1] = (__bf16)a0.y; aF[0][2] = (__bf16)a0.z; aF[0][3] = (__bf16)a0.w;
        aF[0][4] = (__bf16)a1.x; aF[0][5] = (__bf16)a1.y; aF[0][6] = (__bf16)a1.z; aF[0][7] = (__bf16)a1.w;
        aF[1][0] = (__bf16)a2.x; aF[1][1] = (__bf16)a2.y; aF[1][2] = (__bf16)a2.z; aF[1][3] = (__bf16)a2.w;
        aF[1][4] = (__bf16)a3.x; aF[1][5] = (__bf16)a3.y; aF[1][6] = (__bf16)a3.z; aF[1][7] = (__bf16)a3.w;
        bf16x8 bF[8];
#pragma unroll
        for (int n = 0; n < 8; ++n)
            bF[n] = *(const bf16x8*)&Bsm[buf][(n * 16 + rsel) * 32 + fsw];
#pragma unroll
        for (int mm = 0; mm < 2; ++mm)
#pragma unroll
            for (int n = 0; n < 8; ++n)
                acc[mm][n] = __builtin_amdgcn_mfma_f32_16x16x32_bf16(aF[mm], bF[n], acc[mm][n], 0, 0, 0);
    };

    float4 e0, e1, e2, e3, o0, o1, o2, o3;
    // prologue: A(0) -> even regs, B(0) -> buf0
    {
        const float4* p0 = (const float4*)(Ap0 + k0);
        const float4* p1 = (const float4*)(Ap1 + k0);
        e0 = p0[0]; e1 = p0[1]; e2 = p1[0]; e3 = p1[1];
        STAGEB(0, k0);
    }
    int kk = k0;
    for (int it = 0; it < 63; ++it) {
        {   // issue tile t+1 (odd)
            const float4* p0 = (const float4*)(Ap0 + kk + 32);
            const float4* p1 = (const float4*)(Ap1 + kk + 32);
            o0 = p0[0]; o1 = p0[1]; o2 = p1[0]; o3 = p1[1];
            STAGEB(1, kk + 32);
        }
        SCHED0;
        asm volatile("s_waitcnt vmcnt(6)");   // t landed; t+1's 6 in flight
        SCHED0;
        __builtin_amdgcn_s_barrier();
        SCHED0;
        COMPUTE(0, e0, e1, e2, e3);
        SCHED0;
        __builtin_amdgcn_s_barrier();
        SCHED0;
        {   // issue tile t+2 (even)
            const float4* p0 = (const float4*)(Ap0 + kk + 64);
            const float4* p1 = (const float4*)(Ap1 + kk + 64);
            e0 = p0[0]; e1 = p0[1]; e2 = p1[0]; e3 = p1[1];
            STAGEB(0, kk + 64);
        }
        SCHED0;
        asm volatile("s_waitcnt vmcnt(6)");
        SCHED0;
        __builtin_amdgcn_s_barrier();
        SCHED0;
        COMPUTE(1, o0, o1, o2, o3);
        SCHED0;
        __builtin_amdgcn_s_barrier();
        SCHED0;
        kk += 64;
    }
    // tail: tiles 126 (even, buf0) and 127 (odd, buf1)
    {
        const float4* p0 = (const float4*)(Ap0 + kk + 32);
        const float4* p1 = (const float4*)(Ap1 + kk + 32);
        o0 = p0[0]; o1 = p0[1]; o2 = p1[0]; o3 = p1[1];
        STAGEB(1, kk + 32);
    }
    SCHED0;
    asm volatile("s_waitcnt vmcnt(6)");
    SCHED0;
    __builtin_amdgcn_s_barrier();
    SCHED0;
    COMPUTE(0, e0, e1, e2, e3);
    SCHED0;
    __builtin_amdgcn_s_barrier();
    SCHED0;
    asm volatile("s_waitcnt vmcnt(0)");
    SCHED0;
    __builtin_amdgcn_s_barrier();
    SCHED0;
    COMPUTE(1, o0, o1, o2, o3);

    const int cq = (lane >> 4) * 4, cr = lane & 15;
#pragma unroll
    for (int mm = 0; mm < 2; ++mm)
#pragma unroll
        for (int n = 0; n < 8; ++n) {
            int col = colStart + n * 16 + cr;
#pragma unroll
            for (int jj = 0; jj < 4; ++jj) {
                int row = rowStart + wave * 32 + mm * 16 + cq + jj;
                atomicAdd(&C[(size_t)row * 512 + col], acc[mm][n][jj]);
            }
        }
}

// ---------------------------------------------------------------------------
// Fused per-node SDPA (4 branches, 8x8 softmax) + branch sum + RMSNorm*g2
// S12 inputs plain bf16; y output swz bf16.
// ---------------------------------------------------------------------------
struct SP12 { const u16* p[12]; };
__global__ __launch_bounds__(256) void sdpa_fused(SP12 sp, const float* __restrict__ g2,
                                                  u16* __restrict__ y) {
    __shared__ float qb[4][8][65], kb[4][8][65], vb[4][8][65];
    __shared__ float aw[4][64];
    __shared__ float red[4];
    const int n = blockIdx.x, tid = threadIdx.x;
    const size_t base = (size_t)n * 512;
    const int e0 = tid * 2, hs = e0 >> 6, ds = e0 & 63;

#pragma unroll
    for (int br = 0; br < 4; ++br) {
        unsigned u;
        u = *(const unsigned*)(sp.p[br * 3 + 0] + base + e0);
        qb[br][hs][ds] = bf2f(u & 0xffffu); qb[br][hs][ds + 1] = bf2f(u >> 16);
        u = *(const unsigned*)(sp.p[br * 3 + 1] + base + e0);
        kb[br][hs][ds] = bf2f(u & 0xffffu); kb[br][hs][ds + 1] = bf2f(u >> 16);
        u = *(const unsigned*)(sp.p[br * 3 + 2] + base + e0);
        vb[br][hs][ds] = bf2f(u & 0xffffu); vb[br][hs][ds + 1] = bf2f(u >> 16);
    }
    __syncthreads();

    const int b = tid >> 6, h = (tid >> 3) & 7, g = tid & 7;
    float s = 0.f;
    const float* qr = &qb[b][h][0];
    const float* kr = &kb[b][g][0];
#pragma unroll
    for (int j = 0; j < 64; ++j) s += qr[j] * kr[j];
    s *= 0.125f;
    float mx = s;
#pragma unroll
    for (int o = 1; o < 8; o <<= 1) mx = fmaxf(mx, __shfl_xor(mx, o));
    float p = expf(s - mx);
    float sm = p;
#pragma unroll
    for (int o = 1; o < 8; o <<= 1) sm += __shfl_xor(sm, o);
    aw[b][(h << 3) | g] = p / sm;
    __syncthreads();

    float o0 = 0.f, o1 = 0.f;
#pragma unroll
    for (int bb = 0; bb < 4; ++bb)
#pragma unroll
        for (int gg = 0; gg < 8; ++gg) {
            float a = aw[bb][(hs << 3) | gg];
            o0 += a * vb[bb][gg][ds];
            o1 += a * vb[bb][gg][ds + 1];
        }

    float ss = o0 * o0 + o1 * o1;
#pragma unroll
    for (int o = 32; o; o >>= 1) ss += __shfl_down(ss, o);
    if ((tid & 63) == 0) red[tid >> 6] = ss;
    __syncthreads();
    float tot = red[0] + red[1] + red[2] + red[3];
    float rs = rsqrtf(tot * (1.0f / 512.0f) + 1e-6f);
    unsigned pack = (unsigned)f2bf(o0 * rs * g2[e0]) | ((unsigned)f2bf(o1 * rs * g2[e0 + 1]) << 16);
    ((unsigned*)y)[(size_t)n * 256 + (tid ^ (((n >> 1) & 3) << 2))] = pack;  // swz out
}

// ---------------------------------------------------------------------------
extern "C" void kernel_launch(void* const* d_in, const int* in_sizes, int n_in,
                              void* d_out, int out_size, void* d_ws, size_t ws_size,
                              hipStream_t stream) {
    (void)in_sizes; (void)n_in; (void)out_size; (void)ws_size;
    const int N = 4096, M = 16384, E = 512;

    const float* x_node = (const float*)d_in[0];
    const float* x_edge = (const float*)d_in[1];
    const float* adj    = (const float*)d_in[2];
    const float* Wp1_he = (const float*)d_in[15];
    const float* Wp1_eh = (const float*)d_in[16];
    const float* Wp1_ee = (const float*)d_in[17];
    const float* g_n = (const float*)d_in[18];
    const float* g_e = (const float*)d_in[19];
    const float* g2  = (const float*)d_in[20];
    const float* Wf1 = (const float*)d_in[21];
    const float* bf1 = (const float*)d_in[22];
    const float* Wf2 = (const float*)d_in[23];
    const float* bf2 = (const float*)d_in[24];

    // ---- workspace ----
    char* p = (char*)d_ws;
    auto alloc = [&](size_t b) { char* r = p; p += (b + 255) & ~(size_t)255; return r; };
    const size_t NP = (size_t)N * E;
    const size_t WSZ = (size_t)E * E;
    u16* h    = (u16*)alloc(NP * 2);                  // swz
    u16* e    = (u16*)alloc((size_t)M * E * 2);       // plain
    u16* eT   = (u16*)alloc((size_t)M * E * 2);       // swz (512 x 16384)
    u16* Wt   = (u16*)alloc(12 * WSZ * 2);            // swz
    u16* Wf1T = (u16*)alloc((size_t)2048 * 512 * 2);  // swz
    u16* Wf2T = (u16*)alloc((size_t)512 * 2048 * 2);  // swz
    float* F3 = (float*)alloc(3 * NP * 4);            // Pee, Peh, Phe fp32 acc
    u16* P3b  = (u16*)alloc(3 * NP * 2);              // swz
    u16* Ahb  = (u16*)alloc(NP * 2);                  // swz
    u16* S12  = (u16*)alloc(12 * NP * 2);             // plain
    u16* y    = (u16*)alloc(NP * 2);                  // swz
    u16* t    = (u16*)alloc((size_t)N * 2048 * 2);    // swz

    // ---- 1. weight transposes (swz out) ----
    W12 w12;
    for (int i = 0; i < 12; ++i) { w12.in[i] = (const float*)d_in[3 + i]; w12.out[i] = Wt + i * WSZ; }
    transpose_cvt12<<<dim3(16, 16, 12), 256, 0, stream>>>(w12);
    transpose_cvt<<<dim3(64, 16), 256, 0, stream>>>(Wf1, Wf1T, 512, 2048);
    transpose_cvt<<<dim3(16, 64), 256, 0, stream>>>(Wf2, Wf2T, 2048, 512);

    // ---- 2. RMSNorms + eT + sparse Ah ----
    rmsnorm_bf16<true><<<N, 256, 0, stream>>>(x_node, g_n, h);
    rmsnorm_bf16<false><<<M, 256, 0, stream>>>(x_edge, g_e, e);
    transpose_u16<<<dim3(16, 512), 256, 0, stream>>>(e, eT, M, 512);
    adj_spmm<<<1024, 256, 0, stream>>>(adj, h, Ahb);

    // ---- 3. big GEMMs: P = Wp1 @ e (3 batched, splitK=4, A-in-reg) ----
    hipMemsetAsync(F3, 0, 3 * NP * 4, stream);
    Big3 bp; bp.A[0] = Wp1_ee; bp.A[1] = Wp1_eh; bp.A[2] = Wp1_he;
    gemm_f32a<<<dim3(4, 32, 12), 256, 0, stream>>>(bp, eT, F3, M, 4, 4096);
    cvt_f32_bf16<true><<<2048, 256, 0, stream>>>(F3, P3b, 3 * NP / 8);
    const u16* Peeb = P3b + 0 * NP;
    const u16* Pehb = P3b + 1 * NP;
    const u16* Pheb = P3b + 2 * NP;

    // ---- 4. 12 batched projections ----
    Small12 sb;
    const u16* aList[12] = {Ahb, h, h, Peeb, Peeb, h, Pehb, h, h, h, Pheb, h};
    const int wList[12]  = {0, 1, 2, 3, 4, 5, 9, 10, 11, 6, 7, 8};
    for (int i = 0; i < 12; ++i) {
        sb.A[i] = aList[i];
        sb.W[i] = Wt + wList[i] * WSZ;
        sb.C[i] = S12 + i * NP;
    }
    gemm_small12<<<dim3(4, 32, 12), 256, 0, stream>>>(sb);

    // ---- 5. SDPA + sum + RMSNorm -> y (swz) ----
    SP12 sp;
    for (int i = 0; i < 12; ++i) sp.p[i] = S12 + i * NP;
    sdpa_fused<<<N, 256, 0, stream>>>(sp, g2, y);

    // ---- 6. FFN ----
    gemm_bt<1><<<dim3(16, 32, 1), 256, 0, stream>>>(y, Wf1T, t, bf1, 2048, 512, 512);
    hipMemsetAsync(d_out, 0, NP * 4, stream);
    gemm_bt<3><<<dim3(4, 32, 2), 256, 0, stream>>>(t, Wf2T, d_out, bf2, 512, 2048, 1024);
}

// Round 12
// 608.833 us; speedup vs baseline: 1.2665x; 1.2665x over previous
//
#include <hip/hip_runtime.h>
#include <cstdint>

// ---------------------------------------------------------------------------
// Block_7584912244953 on MI355X (gfx950).
//   P_xx = Wp1_xx @ e (3 big GEMMs, fp32 A staged via global_load_lds,
//                      cvt->bf16 in registers after ds_read; split-K atomics)
//   Ah   = adj @ h    (sparse ballot-scan gather, deg~8)
//   12 batched projections -> per-node 8x8 SDPA -> FFN
// ALL GEMMs use the R7-verified counted-vmcnt dist-1 schedule: dbuf LDS,
// raw s_barrier, bare "s_waitcnt vmcnt(N)" (N = loads just issued), sched
// pins. Loads for tile t+1 stay in flight across the barrier.
// bf16 "swz" layout: 16B-chunk c of row r stored at c ^ ((r>>1)&3) within each
// 64B window -> MFMA fragment ds_read_b128 is 2-way (free).
// fp32 A tiles: per-lane SOURCE slot swizzle slot^(row&7) on 16B slots of the
// 128B row; fragment reads XOR the same involution.
// ---------------------------------------------------------------------------

typedef unsigned short u16;
typedef __bf16 bf16x8 __attribute__((ext_vector_type(8)));
typedef float f32x4 __attribute__((ext_vector_type(4)));

__device__ __forceinline__ u16 f2bf(float f) {
    unsigned u = __float_as_uint(f);
    return (u16)((u + 0x7fffu + ((u >> 16) & 1u)) >> 16);  // RNE
}
__device__ __forceinline__ float bf2f(u16 u) { return __uint_as_float(((unsigned)u) << 16); }
__device__ __forceinline__ float gelu_exact(float x) {
    return 0.5f * x * (1.0f + erff(x * 0.70710678118654752f));
}

__device__ __forceinline__ void gload_lds16(const void* g, void* l) {
    __builtin_amdgcn_global_load_lds(
        (const __attribute__((address_space(1))) unsigned int*)(uintptr_t)g,
        (__attribute__((address_space(3))) unsigned int*)(unsigned int)(uintptr_t)l,
        16, 0, 0);
}

#define SCHED0 __builtin_amdgcn_sched_barrier(0)

// bijective XCD-aware block swizzle (gridDim product % 8 == 0)
__device__ __forceinline__ void swz_block(int& bx, int& by, int& bz) {
    const int nx = gridDim.x, ny = gridDim.y;
    const int nwg = nx * ny * gridDim.z;
    int lin = blockIdx.x + nx * (blockIdx.y + ny * blockIdx.z);
    const int chunk = nwg >> 3;
    lin = (lin & 7) * chunk + (lin >> 3);
    bx = lin % nx;
    lin /= nx;
    by = lin % ny;
    bz = lin / ny;
}

// ---------------------------------------------------------------------------
// fp32 -> bf16 convert; SWZ=true emits swz layout (assumes 512-elem rows)
// ---------------------------------------------------------------------------
template <bool SWZ>
__global__ __launch_bounds__(256) void cvt_f32_bf16(const float* __restrict__ in,
                                                    u16* __restrict__ out, size_t n8) {
    size_t i = (size_t)blockIdx.x * 256 + threadIdx.x;
    size_t stride = (size_t)gridDim.x * 256;
    for (; i < n8; i += stride) {
        float4 a = ((const float4*)in)[i * 2];
        float4 b = ((const float4*)in)[i * 2 + 1];
        u16 r[8] = {f2bf(a.x), f2bf(a.y), f2bf(a.z), f2bf(a.w),
                    f2bf(b.x), f2bf(b.y), f2bf(b.z), f2bf(b.w)};
        size_t o = i;
        if constexpr (SWZ) o = (i & ~(size_t)63) | ((i & 63) ^ ((i >> 7) & 3));
        ((uint4*)out)[o] = *(const uint4*)r;
    }
}

// ---------------------------------------------------------------------------
// fp32 (RxC) -> bf16 transposed (CxR), swz output layout
// ---------------------------------------------------------------------------
__global__ __launch_bounds__(256) void transpose_cvt(const float* __restrict__ in,
                                                     u16* __restrict__ out, int R, int C) {
    __shared__ float tile[32][33];
    int c0 = blockIdx.x * 32, r0 = blockIdx.y * 32;
    int tx = threadIdx.x & 31, ty = threadIdx.x >> 5;
#pragma unroll
    for (int i = 0; i < 4; ++i)
        tile[ty + i * 8][tx] = in[(size_t)(r0 + ty + i * 8) * C + c0 + tx];
    __syncthreads();
#pragma unroll
    for (int i = 0; i < 4; ++i) {
        int orow = c0 + ty + i * 8;
        out[(size_t)orow * R + ((r0 + tx) ^ (((orow >> 1) & 3) << 3))] = f2bf(tile[tx][ty + i * 8]);
    }
}

struct W12 { const float* in[12]; u16* out[12]; };
__global__ __launch_bounds__(256) void transpose_cvt12(W12 w) {
    __shared__ float tile[32][33];
    const float* in = w.in[blockIdx.z];
    u16* out = w.out[blockIdx.z];
    int c0 = blockIdx.x * 32, r0 = blockIdx.y * 32;
    int tx = threadIdx.x & 31, ty = threadIdx.x >> 5;
#pragma unroll
    for (int i = 0; i < 4; ++i)
        tile[ty + i * 8][tx] = in[(size_t)(r0 + ty + i * 8) * 512 + c0 + tx];
    __syncthreads();
#pragma unroll
    for (int i = 0; i < 4; ++i) {
        int orow = c0 + ty + i * 8;
        out[(size_t)orow * 512 + ((r0 + tx) ^ (((orow >> 1) & 3) << 3))] = f2bf(tile[tx][ty + i * 8]);
    }
}

// bf16 (RxC, plain) -> bf16 transposed (CxR, swz)
__global__ __launch_bounds__(256) void transpose_u16(const u16* __restrict__ in,
                                                     u16* __restrict__ out, int R, int C) {
    __shared__ u16 tile[32][34];
    int c0 = blockIdx.x * 32, r0 = blockIdx.y * 32;
    int tx = threadIdx.x & 31, ty = threadIdx.x >> 5;
#pragma unroll
    for (int i = 0; i < 4; ++i)
        tile[ty + i * 8][tx] = in[(size_t)(r0 + ty + i * 8) * C + c0 + tx];
    __syncthreads();
#pragma unroll
    for (int i = 0; i < 4; ++i) {
        int orow = c0 + ty + i * 8;
        out[(size_t)orow * R + ((r0 + tx) ^ (((orow >> 1) & 3) << 3))] = tile[tx][ty + i * 8];
    }
}

// ---------------------------------------------------------------------------
// RMSNorm (rows x 512) fp32 -> bf16; SWZ selects output layout
// ---------------------------------------------------------------------------
template <bool SWZ>
__global__ __launch_bounds__(256) void rmsnorm_bf16(const float* __restrict__ x,
                                                    const float* __restrict__ g,
                                                    u16* __restrict__ out) {
    int row = blockIdx.x, tid = threadIdx.x;
    const float* xr = x + (size_t)row * 512;
    float2 v = *(const float2*)(xr + tid * 2);
    float ss = v.x * v.x + v.y * v.y;
#pragma unroll
    for (int o = 32; o; o >>= 1) ss += __shfl_down(ss, o);
    __shared__ float red[4];
    if ((tid & 63) == 0) red[tid >> 6] = ss;
    __syncthreads();
    float tot = red[0] + red[1] + red[2] + red[3];
    float rs = rsqrtf(tot * (1.0f / 512.0f) + 1e-6f);
    unsigned pack = (unsigned)f2bf(v.x * rs * g[tid * 2]) |
                    ((unsigned)f2bf(v.y * rs * g[tid * 2 + 1]) << 16);
    int o32 = SWZ ? (tid ^ (((row >> 1) & 3) << 2)) : tid;
    ((unsigned*)out)[(size_t)row * 256 + o32] = pack;
}

// ---------------------------------------------------------------------------
// Sparse Ah = adj @ h (adj ~0.2% dense binary). One wave per node. swz h/out.
// ---------------------------------------------------------------------------
__global__ __launch_bounds__(256) void adj_spmm(const float* __restrict__ adj,
                                                const u16* __restrict__ h,
                                                u16* __restrict__ out) {
    const int wave = threadIdx.x >> 6, lane = threadIdx.x & 63;
    const int n = blockIdx.x * 4 + wave;
    const float* arow = adj + (size_t)n * 4096;
    float acc[8] = {0.f, 0.f, 0.f, 0.f, 0.f, 0.f, 0.f, 0.f};
    for (int j = 0; j < 64; ++j) {
        float v = arow[j * 64 + lane];
        unsigned long long mask = __ballot(v != 0.0f);
        while (mask) {
            int bit = __ffsll((long long)mask) - 1;
            mask &= mask - 1;
            int m = j * 64 + bit;
            float w = __shfl(v, bit);
            int cs = (lane & ~3) | ((lane & 3) ^ ((m >> 1) & 3));
            uint4 q = *(const uint4*)(h + (size_t)m * 512 + cs * 8);
            const u16* qu = (const u16*)&q;
#pragma unroll
            for (int t = 0; t < 8; ++t) acc[t] += w * bf2f(qu[t]);
        }
    }
    int co = (lane & ~3) | ((lane & 3) ^ ((n >> 1) & 3));
    u16 r[8];
#pragma unroll
    for (int t = 0; t < 8; ++t) r[t] = f2bf(acc[t]);
    *(uint4*)(out + (size_t)n * 512 + co * 8) = *(const uint4*)r;
}

// ---------------------------------------------------------------------------
// bf16 GEMM tile body (counted-vmcnt dist-1 dbuf): 128x128 tile, BK=32,
// 4 waves (2x2), 4x4 frags. A, Bt swz bf16. Per iter: STAGE(buf^1,t+1)
// [4 loads] -> vmcnt(4) -> s_barrier -> COMPUTE(buf) -> s_barrier.
// MODE: 0 bf16 plain store, 1 bf16 bias+gelu swz store, 3 f32 atomicAdd(+bias)
// ---------------------------------------------------------------------------
template <int MODE>
__device__ __forceinline__ void gemm_tile_body(const u16* __restrict__ A,
                                               const u16* __restrict__ Bt,
                                               int N, int K, int k_begin, int k_end,
                                               int rowStart, int colStart,
                                               void* __restrict__ C,
                                               const float* __restrict__ bias) {
    __shared__ u16 Asm[2][4096];
    __shared__ u16 Bsm[2][4096];
    const int tid = threadIdx.x;
    const int wave = tid >> 6, lane = tid & 63;
    const int wr = wave >> 1, wc = wave & 1;

    f32x4 acc[4][4];
#pragma unroll
    for (int m = 0; m < 4; ++m)
#pragma unroll
        for (int n = 0; n < 4; ++n) acc[m][n] = f32x4{0.f, 0.f, 0.f, 0.f};

    const int off0 = (wave * 2 + 0) * 1024 + lane * 16;  // byte in 8KB tile
    const int off1 = (wave * 2 + 1) * 1024 + lane * 16;
    const int r0 = off0 >> 6, k0e = (off0 & 63) >> 1;
    const int r1 = off1 >> 6, k1e = (off1 & 63) >> 1;
    const size_t Arow0 = (size_t)(rowStart + r0) * K + k0e;
    const size_t Arow1 = (size_t)(rowStart + r1) * K + k1e;
    const size_t Brow0 = (size_t)(colStart + r0) * K + k0e;
    const size_t Brow1 = (size_t)(colStart + r1) * K + k1e;
    const int ws0 = (wave * 2 + 0) * 512, ws1 = (wave * 2 + 1) * 512;

    const int rsel = lane & 15, ksel = lane >> 4;
    const int fsw = (ksel ^ ((rsel >> 1) & 3)) << 3;  // swz fragment chunk

    auto STAGE = [&](int buf, int kk) {
        gload_lds16(A + Arow0 + kk, &Asm[buf][ws0]);
        gload_lds16(A + Arow1 + kk, &Asm[buf][ws1]);
        gload_lds16(Bt + Brow0 + kk, &Bsm[buf][ws0]);
        gload_lds16(Bt + Brow1 + kk, &Bsm[buf][ws1]);
    };
    auto COMPUTE = [&](int buf) {
        bf16x8 aF[4], bF[4];
#pragma unroll
        for (int m = 0; m < 4; ++m)
            aF[m] = *(const bf16x8*)&Asm[buf][(wr * 64 + m * 16 + rsel) * 32 + fsw];
#pragma unroll
        for (int n = 0; n < 4; ++n)
            bF[n] = *(const bf16x8*)&Bsm[buf][(wc * 64 + n * 16 + rsel) * 32 + fsw];
#pragma unroll
        for (int m = 0; m < 4; ++m)
#pragma unroll
            for (int n = 0; n < 4; ++n)
                acc[m][n] = __builtin_amdgcn_mfma_f32_16x16x32_bf16(aF[m], bF[n], acc[m][n], 0, 0, 0);
    };

    const int nt = (k_end - k_begin) >> 5;
    STAGE(0, k_begin);
    asm volatile("s_waitcnt vmcnt(0)");
    SCHED0;
    __builtin_amdgcn_s_barrier();
    SCHED0;
    int cur = 0;
    for (int t = 0; t < nt - 1; ++t) {
        STAGE(cur ^ 1, k_begin + (t + 1) * 32);
        SCHED0;
        asm volatile("s_waitcnt vmcnt(4)");   // tile t landed; t+1 in flight
        SCHED0;
        __builtin_amdgcn_s_barrier();
        SCHED0;
        COMPUTE(cur);
        SCHED0;
        __builtin_amdgcn_s_barrier();
        SCHED0;
        cur ^= 1;
    }
    asm volatile("s_waitcnt vmcnt(0)");
    SCHED0;
    __builtin_amdgcn_s_barrier();
    SCHED0;
    COMPUTE(cur);

    const int cq = (lane >> 4) * 4, cr = lane & 15;
#pragma unroll
    for (int m = 0; m < 4; ++m) {
#pragma unroll
        for (int n = 0; n < 4; ++n) {
            int col = colStart + wc * 64 + n * 16 + cr;
#pragma unroll
            for (int j = 0; j < 4; ++j) {
                int row = rowStart + wr * 64 + m * 16 + cq + j;
                float v = acc[m][n][j];
                if constexpr (MODE == 0) {
                    ((u16*)C)[(size_t)row * N + col] = f2bf(v);
                } else if constexpr (MODE == 1) {
                    v = gelu_exact(v + bias[col]);
                    ((u16*)C)[(size_t)row * N + (col ^ (((row >> 1) & 3) << 3))] = f2bf(v);
                } else {
                    if (bias) v += bias[col];
                    atomicAdd(&((float*)C)[(size_t)row * N + col], v);
                }
            }
        }
    }
}

template <int MODE>
__global__ __launch_bounds__(256) void gemm_bt(const u16* __restrict__ A,
                                               const u16* __restrict__ Bt,
                                               void* __restrict__ C,
                                               const float* __restrict__ bias,
                                               int N, int K, int kLen) {
    int bx, by, bz;
    swz_block(bx, by, bz);
    const float* bb = (MODE == 3) ? ((bz == 0) ? bias : nullptr) : bias;
    int kb = bz * kLen;
    gemm_tile_body<MODE>(A, Bt, N, K, kb, kb + kLen, by * 128, bx * 128, C, bb);
}

// 12 batched projections: C[z](4096x512) = A[z] @ W[z]^T (plain bf16 out)
struct Small12 { const u16* A[12]; const u16* W[12]; u16* C[12]; };
__global__ __launch_bounds__(256) void gemm_small12(Small12 s) {
    int bx, by, bz;
    swz_block(bx, by, bz);
    gemm_tile_body<0>(s.A[bz], s.W[bz], 512, 512, 0, 512, by * 128, bx * 128, s.C[bz], nullptr);
}

// ---------------------------------------------------------------------------
// Big GEMM (R7-exact), fp32 A: C(4096x512) += A(4096xK fp32) @ Bt(512xK swz).
// Counted-vmcnt dist-1 dbuf. A staged fp32 via global_load_lds with per-lane
// SOURCE slot swizzle; cvt fp32->bf16 in registers after ds_read.
// Per iter: STAGE(buf^1,t+1) [6 loads] -> vmcnt(6) -> s_barrier ->
//           COMPUTE(buf) -> s_barrier.
// ---------------------------------------------------------------------------
struct Big3 { const float* A[3]; };
__global__ __launch_bounds__(256, 2) void gemm_f32a(Big3 ba, const u16* __restrict__ Bt,
                                                    float* __restrict__ C0, int K,
                                                    int zPerMat, int kLen) {
    __shared__ float Afs[2][4096];  // fp32 A tiles, slot-swizzled rows (16KB each)
    __shared__ u16 Bsm[2][4096];    // bf16 B tiles, swz layout (8KB each)
    int bx, by, bz;
    swz_block(bx, by, bz);
    const int mat = bz / zPerMat, ks = bz - mat * zPerMat;
    const float* __restrict__ A = ba.A[mat];
    float* __restrict__ C = C0 + (size_t)mat * (4096 * 512);
    const int rowStart = by * 128, colStart = bx * 128;
    const int k0 = ks * kLen;

    const int tid = threadIdx.x;
    const int wave = tid >> 6, lane = tid & 63;
    const int wr = wave >> 1, wc = wave & 1;

    f32x4 acc[4][4];
#pragma unroll
    for (int mm = 0; mm < 4; ++mm)
#pragma unroll
        for (int n = 0; n < 4; ++n) acc[mm][n] = f32x4{0.f, 0.f, 0.f, 0.f};

    // A staging: 16 slices of 1KB (8 rows x 128B); wave w owns slices 4w..4w+3.
    const int lrow = lane >> 3;
    const int slot = (lane & 7) ^ lrow;
    size_t asrc[4];
    int adst[4];
#pragma unroll
    for (int i = 0; i < 4; ++i) {
        int row = wave * 32 + i * 8 + lrow;
        asrc[i] = (size_t)(rowStart + row) * K + slot * 4;
        adst[i] = (wave * 4 + i) * 256 + lane * 4;
    }

    // B staging (swz bf16): 8 slices of 1KB; wave w owns slices 2w, 2w+1
    const int off0 = (wave * 2 + 0) * 1024 + lane * 16;
    const int off1 = (wave * 2 + 1) * 1024 + lane * 16;
    const int br0 = off0 >> 6, bk0 = (off0 & 63) >> 1;
    const int br1 = off1 >> 6, bk1 = (off1 & 63) >> 1;
    const u16* Bp0 = Bt + (size_t)(colStart + br0) * K + bk0;
    const u16* Bp1 = Bt + (size_t)(colStart + br1) * K + bk1;
    const int ws0 = (wave * 2 + 0) * 512, ws1 = (wave * 2 + 1) * 512;

    const int rsel = lane & 15, ksel = lane >> 4;
    const int fsw = (ksel ^ ((rsel >> 1) & 3)) << 3;

    auto STAGE = [&](int buf, int kk) {
#pragma unroll
        for (int i = 0; i < 4; ++i)
            gload_lds16(A + asrc[i] + kk, &Afs[buf][adst[i]]);
        gload_lds16(Bp0 + kk, &Bsm[buf][ws0]);
        gload_lds16(Bp1 + kk, &Bsm[buf][ws1]);
    };
    auto COMPUTE = [&](int buf) {
        bf16x8 aF[4], bF[4];
#pragma unroll
        for (int mm = 0; mm < 4; ++mm) {
            int R = wr * 64 + mm * 16 + rsel;
            const char* rb = (const char*)&Afs[buf][0] + R * 128;
            f32x4 lo = *(const f32x4*)(rb + ((((ksel << 1) | 0) ^ (R & 7)) << 4));
            f32x4 hi = *(const f32x4*)(rb + ((((ksel << 1) | 1) ^ (R & 7)) << 4));
            aF[mm][0] = (__bf16)lo[0]; aF[mm][1] = (__bf16)lo[1];
            aF[mm][2] = (__bf16)lo[2]; aF[mm][3] = (__bf16)lo[3];
            aF[mm][4] = (__bf16)hi[0]; aF[mm][5] = (__bf16)hi[1];
            aF[mm][6] = (__bf16)hi[2]; aF[mm][7] = (__bf16)hi[3];
        }
#pragma unroll
        for (int n = 0; n < 4; ++n)
            bF[n] = *(const bf16x8*)&Bsm[buf][(wc * 64 + n * 16 + rsel) * 32 + fsw];
#pragma unroll
        for (int mm = 0; mm < 4; ++mm)
#pragma unroll
            for (int n = 0; n < 4; ++n)
                acc[mm][n] = __builtin_amdgcn_mfma_f32_16x16x32_bf16(aF[mm], bF[n], acc[mm][n], 0, 0, 0);
    };

    const int nt = kLen >> 5;
    STAGE(0, k0);
    asm volatile("s_waitcnt vmcnt(0)");
    SCHED0;
    __builtin_amdgcn_s_barrier();
    SCHED0;

    int cur = 0;
    for (int t = 0; t < nt - 1; ++t) {
        STAGE(cur ^ 1, k0 + (t + 1) * 32);     // 6 loads for tile t+1
        SCHED0;
        asm volatile("s_waitcnt vmcnt(6)");    // tile t landed; t+1 stays in flight
        SCHED0;
        __builtin_amdgcn_s_barrier();
        SCHED0;
        COMPUTE(cur);
        SCHED0;
        __builtin_amdgcn_s_barrier();          // all waves done reading buf cur
        SCHED0;
        cur ^= 1;
    }
    asm volatile("s_waitcnt vmcnt(0)");        // last tile landed
    SCHED0;
    __builtin_amdgcn_s_barrier();
    SCHED0;
    COMPUTE(cur);

    const int cq = (lane >> 4) * 4, cr = lane & 15;
#pragma unroll
    for (int mm = 0; mm < 4; ++mm)
#pragma unroll
        for (int n = 0; n < 4; ++n) {
            int col = colStart + wc * 64 + n * 16 + cr;
#pragma unroll
            for (int j = 0; j < 4; ++j) {
                int row = rowStart + wr * 64 + mm * 16 + cq + j;
                atomicAdd(&C[(size_t)row * 512 + col], acc[mm][n][j]);
            }
        }
}

// ---------------------------------------------------------------------------
// Fused per-node SDPA (4 branches, 8x8 softmax) + branch sum + RMSNorm*g2
// S12 inputs plain bf16; y output swz bf16.
// ---------------------------------------------------------------------------
struct SP12 { const u16* p[12]; };
__global__ __launch_bounds__(256) void sdpa_fused(SP12 sp, const float* __restrict__ g2,
                                                  u16* __restrict__ y) {
    __shared__ float qb[4][8][65], kb[4][8][65], vb[4][8][65];
    __shared__ float aw[4][64];
    __shared__ float red[4];
    const int n = blockIdx.x, tid = threadIdx.x;
    const size_t base = (size_t)n * 512;
    const int e0 = tid * 2, hs = e0 >> 6, ds = e0 & 63;

#pragma unroll
    for (int br = 0; br < 4; ++br) {
        unsigned u;
        u = *(const unsigned*)(sp.p[br * 3 + 0] + base + e0);
        qb[br][hs][ds] = bf2f(u & 0xffffu); qb[br][hs][ds + 1] = bf2f(u >> 16);
        u = *(const unsigned*)(sp.p[br * 3 + 1] + base + e0);
        kb[br][hs][ds] = bf2f(u & 0xffffu); kb[br][hs][ds + 1] = bf2f(u >> 16);
        u = *(const unsigned*)(sp.p[br * 3 + 2] + base + e0);
        vb[br][hs][ds] = bf2f(u & 0xffffu); vb[br][hs][ds + 1] = bf2f(u >> 16);
    }
    __syncthreads();

    const int b = tid >> 6, h = (tid >> 3) & 7, g = tid & 7;
    float s = 0.f;
    const float* qr = &qb[b][h][0];
    const float* kr = &kb[b][g][0];
#pragma unroll
    for (int j = 0; j < 64; ++j) s += qr[j] * kr[j];
    s *= 0.125f;
    float mx = s;
#pragma unroll
    for (int o = 1; o < 8; o <<= 1) mx = fmaxf(mx, __shfl_xor(mx, o));
    float p = expf(s - mx);
    float sm = p;
#pragma unroll
    for (int o = 1; o < 8; o <<= 1) sm += __shfl_xor(sm, o);
    aw[b][(h << 3) | g] = p / sm;
    __syncthreads();

    float o0 = 0.f, o1 = 0.f;
#pragma unroll
    for (int bb = 0; bb < 4; ++bb)
#pragma unroll
        for (int gg = 0; gg < 8; ++gg) {
            float a = aw[bb][(hs << 3) | gg];
            o0 += a * vb[bb][gg][ds];
            o1 += a * vb[bb][gg][ds + 1];
        }

    float ss = o0 * o0 + o1 * o1;
#pragma unroll
    for (int o = 32; o; o >>= 1) ss += __shfl_down(ss, o);
    if ((tid & 63) == 0) red[tid >> 6] = ss;
    __syncthreads();
    float tot = red[0] + red[1] + red[2] + red[3];
    float rs = rsqrtf(tot * (1.0f / 512.0f) + 1e-6f);
    unsigned pack = (unsigned)f2bf(o0 * rs * g2[e0]) | ((unsigned)f2bf(o1 * rs * g2[e0 + 1]) << 16);
    ((unsigned*)y)[(size_t)n * 256 + (tid ^ (((n >> 1) & 3) << 2))] = pack;  // swz out
}

// ---------------------------------------------------------------------------
extern "C" void kernel_launch(void* const* d_in, const int* in_sizes, int n_in,
                              void* d_out, int out_size, void* d_ws, size_t ws_size,
                              hipStream_t stream) {
    (void)in_sizes; (void)n_in; (void)out_size; (void)ws_size;
    const int N = 4096, M = 16384, E = 512;

    const float* x_node = (const float*)d_in[0];
    const float* x_edge = (const float*)d_in[1];
    const float* adj    = (const float*)d_in[2];
    const float* Wp1_he = (const float*)d_in[15];
    const float* Wp1_eh = (const float*)d_in[16];
    const float* Wp1_ee = (const float*)d_in[17];
    const float* g_n = (const float*)d_in[18];
    const float* g_e = (const float*)d_in[19];
    const float* g2  = (const float*)d_in[20];
    const float* Wf1 = (const float*)d_in[21];
    const float* bf1 = (const float*)d_in[22];
    const float* Wf2 = (const float*)d_in[23];
    const float* bf2 = (const float*)d_in[24];

    // ---- workspace ----
    char* p = (char*)d_ws;
    auto alloc = [&](size_t b) { char* r = p; p += (b + 255) & ~(size_t)255; return r; };
    const size_t NP = (size_t)N * E;
    const size_t WSZ = (size_t)E * E;
    u16* h    = (u16*)alloc(NP * 2);                  // swz
    u16* e    = (u16*)alloc((size_t)M * E * 2);       // plain
    u16* eT   = (u16*)alloc((size_t)M * E * 2);       // swz (512 x 16384)
    u16* Wt   = (u16*)alloc(12 * WSZ * 2);            // swz
    u16* Wf1T = (u16*)alloc((size_t)2048 * 512 * 2);  // swz
    u16* Wf2T = (u16*)alloc((size_t)512 * 2048 * 2);  // swz
    float* F3 = (float*)alloc(3 * NP * 4);            // Pee, Peh, Phe fp32 acc
    u16* P3b  = (u16*)alloc(3 * NP * 2);              // swz
    u16* Ahb  = (u16*)alloc(NP * 2);                  // swz
    u16* S12  = (u16*)alloc(12 * NP * 2);             // plain
    u16* y    = (u16*)alloc(NP * 2);                  // swz
    u16* t    = (u16*)alloc((size_t)N * 2048 * 2);    // swz

    // ---- 1. weight transposes (swz out) ----
    W12 w12;
    for (int i = 0; i < 12; ++i) { w12.in[i] = (const float*)d_in[3 + i]; w12.out[i] = Wt + i * WSZ; }
    transpose_cvt12<<<dim3(16, 16, 12), 256, 0, stream>>>(w12);
    transpose_cvt<<<dim3(64, 16), 256, 0, stream>>>(Wf1, Wf1T, 512, 2048);
    transpose_cvt<<<dim3(16, 64), 256, 0, stream>>>(Wf2, Wf2T, 2048, 512);

    // ---- 2. RMSNorms + eT + sparse Ah ----
    rmsnorm_bf16<true><<<N, 256, 0, stream>>>(x_node, g_n, h);
    rmsnorm_bf16<false><<<M, 256, 0, stream>>>(x_edge, g_e, e);
    transpose_u16<<<dim3(16, 512), 256, 0, stream>>>(e, eT, M, 512);
    adj_spmm<<<1024, 256, 0, stream>>>(adj, h, Ahb);

    // ---- 3. big GEMMs: P = Wp1 @ e (3 batched, splitK=4) ----
    hipMemsetAsync(F3, 0, 3 * NP * 4, stream);
    Big3 bp; bp.A[0] = Wp1_ee; bp.A[1] = Wp1_eh; bp.A[2] = Wp1_he;
    gemm_f32a<<<dim3(4, 32, 12), 256, 0, stream>>>(bp, eT, F3, M, 4, 4096);
    cvt_f32_bf16<true><<<2048, 256, 0, stream>>>(F3, P3b, 3 * NP / 8);
    const u16* Peeb = P3b + 0 * NP;
    const u16* Pehb = P3b + 1 * NP;
    const u16* Pheb = P3b + 2 * NP;

    // ---- 4. 12 batched projections ----
    Small12 sb;
    const u16* aList[12] = {Ahb, h, h, Peeb, Peeb, h, Pehb, h, h, h, Pheb, h};
    const int wList[12]  = {0, 1, 2, 3, 4, 5, 9, 10, 11, 6, 7, 8};
    for (int i = 0; i < 12; ++i) {
        sb.A[i] = aList[i];
        sb.W[i] = Wt + wList[i] * WSZ;
        sb.C[i] = S12 + i * NP;
    }
    gemm_small12<<<dim3(4, 32, 12), 256, 0, stream>>>(sb);

    // ---- 5. SDPA + sum + RMSNorm -> y (swz) ----
    SP12 sp;
    for (int i = 0; i < 12; ++i) sp.p[i] = S12 + i * NP;
    sdpa_fused<<<N, 256, 0, stream>>>(sp, g2, y);

    // ---- 6. FFN ----
    gemm_bt<1><<<dim3(16, 32, 1), 256, 0, stream>>>(y, Wf1T, t, bf1, 2048, 512, 512);
    hipMemsetAsync(d_out, 0, NP * 4, stream);
    gemm_bt<3><<<dim3(4, 32, 2), 256, 0, stream>>>(t, Wf2T, d_out, bf2, 512, 2048, 1024);
}